// Round 11
// baseline (190.025 us; speedup 1.0000x reference)
//
#include <hip/hip_runtime.h>

#define NH 16
#define SL 2048
#define NB 2
#define DIM 1024
#define N3 3072

typedef __bf16 bf16x8 __attribute__((ext_vector_type(8)));
typedef float f32x4 __attribute__((ext_vector_type(4)));

// async global -> LDS, 16B per lane, wave-uniform LDS base (HW adds lane*16)
#define GLL(gsrc, ldst) \
    __builtin_amdgcn_global_load_lds((const __attribute__((address_space(1))) void*)(gsrc), \
                                     (__attribute__((address_space(3))) void*)(ldst), 16, 0, 0)

static __device__ __forceinline__ unsigned short f2bf(float f) {
    union { float f; unsigned u; } v; v.f = f;
    unsigned r = v.u + 0x7fffu + ((v.u >> 16) & 1u);   // RNE
    return (unsigned short)(r >> 16);
}
static __device__ __forceinline__ float bf2f(unsigned short u) {
    union { unsigned u; float f; } v; v.u = (unsigned)u << 16;
    return v.f;
}

// ---------------- prep (merged): x->bf16 | W^T->bf16 | out_w^T->bf16 ----------------
__global__ __launch_bounds__(256) void prep_k(const float* __restrict__ x,
                                              const float* __restrict__ w,
                                              const float* __restrict__ ow,
                                              unsigned short* __restrict__ xbf,
                                              unsigned short* __restrict__ wT,
                                              unsigned short* __restrict__ owT) {
    __shared__ float tile[32][33];
    int blk = blockIdx.x;
    if (blk < 2048) {                     // cvt x -> xbf, 8 elems/lane
        int i = (blk * 256 + threadIdx.x) * 8;
        float4 v0 = *(const float4*)(x + i);
        float4 v1 = *(const float4*)(x + i + 4);
        ushort4 o0, o1;
        o0.x = f2bf(v0.x); o0.y = f2bf(v0.y); o0.z = f2bf(v0.z); o0.w = f2bf(v0.w);
        o1.x = f2bf(v1.x); o1.y = f2bf(v1.y); o1.z = f2bf(v1.z); o1.w = f2bf(v1.w);
        *(ushort4*)(xbf + i) = o0;
        *(ushort4*)(xbf + i + 4) = o1;
        return;
    }
    const float* in;
    unsigned short* out;
    int R, C, bx, by;
    if (blk < 5120) {                     // weights (1024 x 3072) -> wT (3072 x 1024)
        int idx = blk - 2048;
        in = w; out = wT; R = DIM; C = N3; bx = idx % (N3 / 32); by = idx / (N3 / 32);
    } else {                              // out_w (1024 x 1024) -> owT
        int idx = blk - 5120;
        in = ow; out = owT; R = DIM; C = DIM; bx = idx % (DIM / 32); by = idx / (DIM / 32);
    }
    int tx = threadIdx.x & 31, ty = threadIdx.x >> 5;
    int c0 = bx * 32, r0 = by * 32;
#pragma unroll
    for (int i = 0; i < 4; ++i)
        tile[ty + i * 8][tx] = in[(size_t)(r0 + ty + i * 8) * C + (c0 + tx)];
    __syncthreads();
#pragma unroll
    for (int i = 0; i < 4; ++i)
        out[(size_t)(c0 + ty + i * 8) * R + (r0 + tx)] = f2bf(tile[tx][ty + i * 8]);
}

// ---------------- merged: GEMM1 (qkv, 64x128 tiles) || fuse_madj ----------------
// blocks [0,256): madj stream.  blocks [256,1792): 64x128 gemm tiles ->
// 24 KiB LDS, 6 blocks/CU, 24 waves/CU (was 3 blocks/12 waves at 128x128).
__global__ __launch_bounds__(256) void qkvmadj_k(
    const unsigned short* __restrict__ A,
    const unsigned short* __restrict__ Bt,
    const float* __restrict__ bias,
    unsigned short* __restrict__ Qb,   // (B,H,L,64), pre-scaled by 0.125*log2e
    unsigned short* __restrict__ Kb,   // (B,H,L,64)
    unsigned short* __restrict__ Vt,   // (B,H,64,L)
    const float* __restrict__ adj,
    const int* __restrict__ mask,
    unsigned short* __restrict__ madj) {
    const int K = DIM;
    __shared__ unsigned short As[64][64];     //  8 KiB
    __shared__ unsigned short Bs[128][64];    // 16 KiB

    if (blockIdx.x < 256) {            // ---- madj stream ----
        int t = blockIdx.x * 256 + threadIdx.x;
        const unsigned short NEG = 0xFE96;  // bf16(-9.97e37)
#pragma unroll 1
        for (int it = 0; it < 16; ++it, t += 65536) {
            size_t i = (size_t)t * 8;
            float4 a0 = *(const float4*)(adj + i);
            float4 a1 = *(const float4*)(adj + i + 4);
            int4 m0 = *(const int4*)(mask + i);
            int4 m1 = *(const int4*)(mask + i + 4);
            ushort4 o0, o1;
            o0.x = m0.x ? f2bf(a0.x) : NEG; o0.y = m0.y ? f2bf(a0.y) : NEG;
            o0.z = m0.z ? f2bf(a0.z) : NEG; o0.w = m0.w ? f2bf(a0.w) : NEG;
            o1.x = m1.x ? f2bf(a1.x) : NEG; o1.y = m1.y ? f2bf(a1.y) : NEG;
            o1.z = m1.z ? f2bf(a1.z) : NEG; o1.w = m1.w ? f2bf(a1.w) : NEG;
            *(ushort4*)(madj + i) = o0;
            *(ushort4*)(madj + i + 4) = o1;
        }
        return;
    }

    int bid = blockIdx.x - 256;
    int tid = threadIdx.x;
    int lane = tid & 63, wave = tid >> 6;
    int l15 = lane & 15, g = lane >> 4;
    int wr = wave >> 1, wc = wave & 1;
    int bm = bid / (N3 / 128), bn = bid % (N3 / 128);   // 64 x 24 tiles

    const f32x4 fz = {0.f, 0.f, 0.f, 0.f};
    f32x4 acc[2][4];
#pragma unroll
    for (int m = 0; m < 2; ++m)
#pragma unroll
        for (int n = 0; n < 4; ++n) acc[m][n] = fz;

    int r8 = lane >> 3, u = lane & 7;
    int su = (u ^ r8) << 3;                 // pre-swizzled source column (elements)
    const unsigned short* Ap = A + (size_t)(bm * 64) * K;
    const unsigned short* Bp = Bt + (size_t)(bn * 128) * K;

    for (int k0 = 0; k0 < K; k0 += 64) {
        __syncthreads();
#pragma unroll
        for (int i = 0; i < 2; ++i) {
            int row = i * 32 + wave * 8 + r8;
            GLL(Ap + (size_t)row * K + k0 + su, &As[i * 32 + wave * 8][0]);
        }
#pragma unroll
        for (int i = 0; i < 4; ++i) {
            int row = i * 32 + wave * 8 + r8;
            GLL(Bp + (size_t)row * K + k0 + su, &Bs[i * 32 + wave * 8][0]);
        }
        __syncthreads();
#pragma unroll
        for (int kk = 0; kk < 2; ++kk) {
            bf16x8 af[2], bfr[4];
            int uu = kk * 4 + g;
#pragma unroll
            for (int m = 0; m < 2; ++m)
                af[m] = *(const bf16x8*)&As[wr * 32 + m * 16 + l15][(uu ^ (l15 & 7)) << 3];
#pragma unroll
            for (int n = 0; n < 4; ++n)
                bfr[n] = *(const bf16x8*)&Bs[wc * 64 + n * 16 + l15][(uu ^ (l15 & 7)) << 3];
#pragma unroll
            for (int m = 0; m < 2; ++m)
#pragma unroll
                for (int n = 0; n < 4; ++n)
                    acc[m][n] = __builtin_amdgcn_mfma_f32_16x16x32_bf16(af[m], bfr[n], acc[m][n], 0, 0, 0);
        }
    }
#pragma unroll
    for (int m = 0; m < 2; ++m)
#pragma unroll
        for (int n = 0; n < 4; ++n) {
            int ng = bn * 128 + wc * 64 + n * 16 + l15;
            float bv = bias[ng];
            int h = ng / 192, c = ng % 192;
#pragma unroll
            for (int r = 0; r < 4; ++r) {
                int mg = bm * 64 + wr * 32 + m * 16 + g * 4 + r;
                int b = mg >> 11, l = mg & (SL - 1);
                float v = acc[m][n][r] + bv;
                if (c < 64)
                    Qb[((size_t)(b * NH + h) * SL + l) * 64 + c] = f2bf(v * 0.18033688f); // 0.125*log2e
                else if (c < 128)
                    Kb[((size_t)(b * NH + h) * SL + l) * 64 + (c - 64)] = f2bf(v);
                else
                    Vt[((size_t)(b * NH + h) * 64 + (c - 128)) * SL + l] = f2bf(v);
            }
        }
}

// ---------------- fused flash attention (R8 structure + slope==0 specialization) ----------------
__global__ __launch_bounds__(256) void attn_k(
    const unsigned short* __restrict__ Qb,
    const unsigned short* __restrict__ Kb,
    const unsigned short* __restrict__ Vt,
    const unsigned short* __restrict__ madj,  // (B,L,L) bf16, mask pre-applied
    const float* __restrict__ gamma,
    unsigned short* __restrict__ attout) {    // (B,L,D) bf16
    __shared__ unsigned short Ks[2][64][64];  // linear, XOR-swizzled content
    __shared__ unsigned short Vs[2][64][64];
    __shared__ unsigned Ps[4][16][32];        // per-wave packed-bf16 P, XOR-swizzled u32 cols

    int tid = threadIdx.x, wave = tid >> 6, lane = tid & 63;
    int l15 = lane & 15, g = lane >> 4;
    int logical = ((blockIdx.x & 7) << 7) | (blockIdx.x >> 3);
    int h = logical & 15;
    int gq = logical >> 4;
    int qb = gq & 31;
    int b = gq >> 5;

    size_t bh = (size_t)(b * NH + h);
    const unsigned short* Qp = Qb + bh * SL * 64;
    const unsigned short* Kp = Kb + bh * SL * 64;
    const unsigned short* Vp = Vt + bh * 64 * SL;

    bool alibi = (h < 8);                      // wave-uniform: heads 8..15 have slope 0
    float slope = alibi ? -1.44269504f / (float)(2 << h) : 0.0f;
    float gam = gamma[h] * 1.44269504f;

    int qrow = qb * 64 + wave * 16 + l15;
    bf16x8 qf0 = *(const bf16x8*)&Qp[(size_t)qrow * 64 + g * 8];
    bf16x8 qf1 = *(const bf16x8*)&Qp[(size_t)qrow * 64 + 32 + g * 8];

    const unsigned short* mrow_p = madj + ((size_t)b * SL + qrow) * SL + 4 * g;

    float mrow = -3.0e38f, lrow = 0.f;
    const f32x4 fz = {0.f, 0.f, 0.f, 0.f};
    f32x4 o[4];
#pragma unroll
    for (int dt = 0; dt < 4; ++dt) o[dt] = fz;

    int bpa = 80 * g;              // bpermute src-lane 20g+r
    unsigned xsw = (unsigned)((l15 & 7) << 2);

    int r8 = lane >> 3, u = lane & 7;
    int su = (u ^ r8) << 3;        // pre-swizzled source column (elements)

    // prologue: stage tile 0 into buffer 0; madj tile 0 into registers
#pragma unroll
    for (int i = 0; i < 2; ++i) {
        int row = i * 32 + wave * 8 + r8;
        GLL(Kp + ((size_t)row << 6) + su, &Ks[0][i * 32 + wave * 8][0]);
        GLL(Vp + (size_t)row * SL + su, &Vs[0][i * 32 + wave * 8][0]);
    }
    ushort4 mv_cur[4], mv_nxt[4];
#pragma unroll
    for (int jt = 0; jt < 4; ++jt) mv_cur[jt] = *(const ushort4*)(mrow_p + 16 * jt);

    for (int jb = 0; jb < 32; ++jb) {
        int bb = jb & 1;
        __syncthreads();   // drains vmcnt: buf[bb] + mv for this tile are resident

        // issue next tile's staging: K/V -> LDS (other buffer), madj -> regs.
        if (jb < 31) {
#pragma unroll
            for (int i = 0; i < 2; ++i) {
                int row = i * 32 + wave * 8 + r8;
                GLL(Kp + ((size_t)((jb + 1) * 64 + row) << 6) + su, &Ks[bb ^ 1][i * 32 + wave * 8][0]);
                GLL(Vp + (size_t)row * SL + (jb + 1) * 64 + su, &Vs[bb ^ 1][i * 32 + wave * 8][0]);
            }
#pragma unroll
            for (int jt = 0; jt < 4; ++jt)
                mv_nxt[jt] = *(const ushort4*)(mrow_p + (jb + 1) * 64 + 16 * jt);
        }

        // S^T = K Q^T : D[col = q-row = l15][row = k-local = 4g+r]
        f32x4 s[4];
        __builtin_amdgcn_s_setprio(1);
#pragma unroll
        for (int jt = 0; jt < 4; ++jt) {
            int row = jt * 16 + l15;
            bf16x8 kf0 = *(const bf16x8*)&Ks[bb][row][(g ^ (l15 & 7)) << 3];
            bf16x8 kf1 = *(const bf16x8*)&Ks[bb][row][((4 + g) ^ (l15 & 7)) << 3];
            s[jt] = __builtin_amdgcn_mfma_f32_16x16x32_bf16(kf0, qf0, fz, 0, 0, 0);
            s[jt] = __builtin_amdgcn_mfma_f32_16x16x32_bf16(kf1, qf1, s[jt], 0, 0, 0);
        }
        __builtin_amdgcn_s_setprio(0);

        // scores: val[4jt+r] for k = 16jt + 4g + r  (mv_cur resident -> no vmem wait)
        float val[16];
        if (alibi) {
            float d0 = (float)(qrow - jb * 64 - 4 * g);
#pragma unroll
            for (int jt = 0; jt < 4; ++jt) {
                float djt = d0 - (float)(16 * jt);
                val[4 * jt + 0] = fmaf(gam, bf2f(mv_cur[jt].x), fmaf(slope, fabsf(djt),       s[jt][0]));
                val[4 * jt + 1] = fmaf(gam, bf2f(mv_cur[jt].y), fmaf(slope, fabsf(djt - 1.f), s[jt][1]));
                val[4 * jt + 2] = fmaf(gam, bf2f(mv_cur[jt].z), fmaf(slope, fabsf(djt - 2.f), s[jt][2]));
                val[4 * jt + 3] = fmaf(gam, bf2f(mv_cur[jt].w), fmaf(slope, fabsf(djt - 3.f), s[jt][3]));
            }
        } else {
#pragma unroll
            for (int jt = 0; jt < 4; ++jt) {
                val[4 * jt + 0] = fmaf(gam, bf2f(mv_cur[jt].x), s[jt][0]);
                val[4 * jt + 1] = fmaf(gam, bf2f(mv_cur[jt].y), s[jt][1]);
                val[4 * jt + 2] = fmaf(gam, bf2f(mv_cur[jt].z), s[jt][2]);
                val[4 * jt + 3] = fmaf(gam, bf2f(mv_cur[jt].w), s[jt][3]);
            }
        }

        // row max: in-lane tree + cross-group
        float m0 = fmaxf(fmaxf(val[0], val[1]), fmaxf(val[2], val[3]));
        float m1 = fmaxf(fmaxf(val[4], val[5]), fmaxf(val[6], val[7]));
        float m2 = fmaxf(fmaxf(val[8], val[9]), fmaxf(val[10], val[11]));
        float m3 = fmaxf(fmaxf(val[12], val[13]), fmaxf(val[14], val[15]));
        float mx = fmaxf(fmaxf(m0, m1), fmaxf(m2, m3));
        mx = fmaxf(mx, __shfl_xor(mx, 16));
        mx = fmaxf(mx, __shfl_xor(mx, 32));

        // defer-max (T13)
        if (!__all(mx <= mrow + 8.0f)) {
            float mnew = fmaxf(mrow, mx);
            float sc = __builtin_exp2f(mrow - mnew);
            mrow = mnew;
            lrow *= sc;
            float scl[4];
#pragma unroll
            for (int r = 0; r < 4; ++r)
                scl[r] = __int_as_float(__builtin_amdgcn_ds_bpermute(bpa + 4 * r, __float_as_int(sc)));
#pragma unroll
            for (int dt = 0; dt < 4; ++dt)
#pragma unroll
                for (int r = 0; r < 4; ++r) o[dt][r] *= scl[r];
        }

        // p = exp2(val - mrow), row-sum
#pragma unroll
        for (int t = 0; t < 16; ++t) val[t] = __builtin_exp2f(val[t] - mrow);
        float s0 = (val[0] + val[1]) + (val[2] + val[3]);
        float s1 = (val[4] + val[5]) + (val[6] + val[7]);
        float s2 = (val[8] + val[9]) + (val[10] + val[11]);
        float s3 = (val[12] + val[13]) + (val[14] + val[15]);
        float rs = (s0 + s1) + (s2 + s3);
        rs += __shfl_xor(rs, 16);
        rs += __shfl_xor(rs, 32);
        lrow += rs;

        // pack P pairs (u32 idx = k/2), per-wave LDS (in-wave lgkm ordering only)
#pragma unroll
        for (int jt = 0; jt < 4; ++jt)
#pragma unroll
            for (int c = 0; c < 2; ++c) {
                union { unsigned u; __bf16 hh[2]; } pk;
                pk.hh[0] = (__bf16)val[4 * jt + 2 * c];
                pk.hh[1] = (__bf16)val[4 * jt + 2 * c + 1];
                Ps[wave][l15][(unsigned)(jt * 8 + g * 2 + c) ^ xsw] = pk.u;
            }

        // PV: A-frag = P[row=l15][k-halves], B-frag = Vs (swizzled read)
        __builtin_amdgcn_s_setprio(1);
#pragma unroll
        for (int h2 = 0; h2 < 2; ++h2) {
            union { uint4 u; bf16x8 v; } pr;
            pr.u = *(const uint4*)&Ps[wave][l15][(unsigned)(16 * h2 + 4 * g) ^ xsw];
#pragma unroll
            for (int dt = 0; dt < 4; ++dt) {
                bf16x8 vf = *(const bf16x8*)&Vs[bb][dt * 16 + l15][((h2 * 4 + g) ^ (l15 & 7)) << 3];
                o[dt] = __builtin_amdgcn_mfma_f32_16x16x32_bf16(pr.v, vf, o[dt], 0, 0, 0);
            }
        }
        __builtin_amdgcn_s_setprio(0);

        // rotate madj register buffer (wait coincides with the barrier drain)
#pragma unroll
        for (int jt = 0; jt < 4; ++jt) mv_cur[jt] = mv_nxt[jt];
    }

    // epilogue: redistribute 1/l to output rows 4g+r, store
    float inv = 1.0f / lrow;
    float invr[4];
#pragma unroll
    for (int r = 0; r < 4; ++r)
        invr[r] = __int_as_float(__builtin_amdgcn_ds_bpermute(bpa + 4 * r, __float_as_int(inv)));
#pragma unroll
    for (int dt = 0; dt < 4; ++dt)
#pragma unroll
        for (int r = 0; r < 4; ++r) {
            int orow = qb * 64 + wave * 16 + 4 * g + r;
            attout[((size_t)b * SL + orow) * DIM + h * 64 + dt * 16 + l15] = f2bf(o[dt][r] * invr[r]);
        }
}

// ---------------- GEMM3: out = attout @ out_w + out_bias (fp32 out) ----------------
// 64x128 tiles -> 512 blocks = 2/CU
__global__ __launch_bounds__(256) void gemm_out_k(
    const unsigned short* __restrict__ A,    // (4096 x 1024) bf16
    const unsigned short* __restrict__ Bt,   // (1024 x 1024) bf16 (out_w^T)
    const float* __restrict__ bias,
    float* __restrict__ Out) {
    const int K = DIM;
    __shared__ unsigned short As[64][64];
    __shared__ unsigned short Bs[128][64];
    int tid = threadIdx.x;
    int lane = tid & 63, wave = tid >> 6;
    int l15 = lane & 15, g = lane >> 4;
    int wr = wave >> 1, wc = wave & 1;
    int bm = blockIdx.x >> 3, bn = blockIdx.x & 7;   // 64 x 8 tiles

    const f32x4 fz = {0.f, 0.f, 0.f, 0.f};
    f32x4 acc[2][4];
#pragma unroll
    for (int m = 0; m < 2; ++m)
#pragma unroll
        for (int n = 0; n < 4; ++n) acc[m][n] = fz;

    int r8 = lane >> 3, u = lane & 7;
    int su = (u ^ r8) << 3;
    const unsigned short* Ap = A + (size_t)(bm * 64) * K;
    const unsigned short* Bp = Bt + (size_t)(bn * 128) * K;

    for (int k0 = 0; k0 < K; k0 += 64) {
        __syncthreads();
#pragma unroll
        for (int i = 0; i < 2; ++i) {
            int row = i * 32 + wave * 8 + r8;
            GLL(Ap + (size_t)row * K + k0 + su, &As[i * 32 + wave * 8][0]);
        }
#pragma unroll
        for (int i = 0; i < 4; ++i) {
            int row = i * 32 + wave * 8 + r8;
            GLL(Bp + (size_t)row * K + k0 + su, &Bs[i * 32 + wave * 8][0]);
        }
        __syncthreads();
#pragma unroll
        for (int kk = 0; kk < 2; ++kk) {
            bf16x8 af[2], bfr[4];
            int uu = kk * 4 + g;
#pragma unroll
            for (int m = 0; m < 2; ++m)
                af[m] = *(const bf16x8*)&As[wr * 32 + m * 16 + l15][(uu ^ (l15 & 7)) << 3];
#pragma unroll
            for (int n = 0; n < 4; ++n)
                bfr[n] = *(const bf16x8*)&Bs[wc * 64 + n * 16 + l15][(uu ^ (l15 & 7)) << 3];
#pragma unroll
            for (int m = 0; m < 2; ++m)
#pragma unroll
                for (int n = 0; n < 4; ++n)
                    acc[m][n] = __builtin_amdgcn_mfma_f32_16x16x32_bf16(af[m], bfr[n], acc[m][n], 0, 0, 0);
        }
    }
#pragma unroll
    for (int m = 0; m < 2; ++m)
#pragma unroll
        for (int n = 0; n < 4; ++n) {
            int ng = bn * 128 + wc * 64 + n * 16 + l15;
            float bv = bias[ng];
#pragma unroll
            for (int r = 0; r < 4; ++r) {
                int mg = bm * 64 + wr * 32 + m * 16 + g * 4 + r;
                Out[(size_t)mg * DIM + ng] = acc[m][n][r] + bv;
            }
        }
}

extern "C" void kernel_launch(void* const* d_in, const int* in_sizes, int n_in,
                              void* d_out, int out_size, void* d_ws, size_t ws_size,
                              hipStream_t stream) {
    const float* x        = (const float*)d_in[0];
    const float* adj      = (const float*)d_in[1];
    const float* weights  = (const float*)d_in[2];
    const float* in_bias  = (const float*)d_in[3];
    const float* out_w    = (const float*)d_in[4];
    const float* out_bias = (const float*)d_in[5];
    const float* gamma    = (const float*)d_in[6];
    const int* mask       = (const int*)d_in[7];   // bool -> int32 per harness contract

    char* ws = (char*)d_ws;
    unsigned short* xbf    = (unsigned short*)(ws);              // 8 MiB
    unsigned short* wT     = (unsigned short*)(ws + 8388608);    // 6 MiB
    unsigned short* owT    = (unsigned short*)(ws + 14680064);   // 2 MiB
    unsigned short* Qb     = (unsigned short*)(ws + 16777216);   // 8 MiB
    unsigned short* Kb     = (unsigned short*)(ws + 25165824);   // 8 MiB
    unsigned short* Vt     = (unsigned short*)(ws + 33554432);   // 8 MiB
    unsigned short* attout = (unsigned short*)(ws + 41943040);   // 8 MiB (total 48 MiB)
    // madj (16.78 MB) lives in d_out: written by qkvmadj_k, read by attn_k,
    // dead before gemm_out_k overwrites d_out with the final result.
    unsigned short* madj   = (unsigned short*)d_out;
    float* out = (float*)d_out;

    prep_k<<<6144, 256, 0, stream>>>(x, weights, out_w, xbf, wT, owT);
    qkvmadj_k<<<1792, 256, 0, stream>>>(xbf, wT, in_bias, Qb, Kb, Vt, adj, mask, madj);
    attn_k<<<NB * NH * (SL / 64), 256, 0, stream>>>(Qb, Kb, Vt, madj, gamma, attout);
    gemm_out_k<<<512, 256, 0, stream>>>(attout, owT, out_bias, out);
}

// Round 12
// 168.580 us; speedup vs baseline: 1.1272x; 1.1272x over previous
//
#include <hip/hip_runtime.h>

#define NH 16
#define SL 2048
#define NB 2
#define DIM 1024
#define N3 3072

typedef __bf16 bf16x8 __attribute__((ext_vector_type(8)));
typedef float f32x4 __attribute__((ext_vector_type(4)));

// async global -> LDS, 16B per lane, wave-uniform LDS base (HW adds lane*16)
#define GLL(gsrc, ldst) \
    __builtin_amdgcn_global_load_lds((const __attribute__((address_space(1))) void*)(gsrc), \
                                     (__attribute__((address_space(3))) void*)(ldst), 16, 0, 0)

static __device__ __forceinline__ unsigned short f2bf(float f) {
    union { float f; unsigned u; } v; v.f = f;
    unsigned r = v.u + 0x7fffu + ((v.u >> 16) & 1u);   // RNE
    return (unsigned short)(r >> 16);
}
static __device__ __forceinline__ float bf2f(unsigned short u) {
    union { unsigned u; float f; } v; v.u = (unsigned)u << 16;
    return v.f;
}

// ---------------- prep (merged): x->bf16 | W^T->bf16 | out_w^T->bf16 ----------------
__global__ __launch_bounds__(256) void prep_k(const float* __restrict__ x,
                                              const float* __restrict__ w,
                                              const float* __restrict__ ow,
                                              unsigned short* __restrict__ xbf,
                                              unsigned short* __restrict__ wT,
                                              unsigned short* __restrict__ owT) {
    __shared__ float tile[32][33];
    int blk = blockIdx.x;
    if (blk < 2048) {                     // cvt x -> xbf, 8 elems/lane
        int i = (blk * 256 + threadIdx.x) * 8;
        float4 v0 = *(const float4*)(x + i);
        float4 v1 = *(const float4*)(x + i + 4);
        ushort4 o0, o1;
        o0.x = f2bf(v0.x); o0.y = f2bf(v0.y); o0.z = f2bf(v0.z); o0.w = f2bf(v0.w);
        o1.x = f2bf(v1.x); o1.y = f2bf(v1.y); o1.z = f2bf(v1.z); o1.w = f2bf(v1.w);
        *(ushort4*)(xbf + i) = o0;
        *(ushort4*)(xbf + i + 4) = o1;
        return;
    }
    const float* in;
    unsigned short* out;
    int R, C, bx, by;
    if (blk < 5120) {                     // weights (1024 x 3072) -> wT (3072 x 1024)
        int idx = blk - 2048;
        in = w; out = wT; R = DIM; C = N3; bx = idx % (N3 / 32); by = idx / (N3 / 32);
    } else {                              // out_w (1024 x 1024) -> owT
        int idx = blk - 5120;
        in = ow; out = owT; R = DIM; C = DIM; bx = idx % (DIM / 32); by = idx / (DIM / 32);
    }
    int tx = threadIdx.x & 31, ty = threadIdx.x >> 5;
    int c0 = bx * 32, r0 = by * 32;
#pragma unroll
    for (int i = 0; i < 4; ++i)
        tile[ty + i * 8][tx] = in[(size_t)(r0 + ty + i * 8) * C + (c0 + tx)];
    __syncthreads();
#pragma unroll
    for (int i = 0; i < 4; ++i)
        out[(size_t)(c0 + ty + i * 8) * R + (r0 + tx)] = f2bf(tile[tx][ty + i * 8]);
}

// ---------------- merged: GEMM1 (qkv, 64x128 tiles) || fuse_madj ----------------
// blocks [0,256): madj stream.  blocks [256,1792): 64x128 gemm tiles ->
// 24 KiB LDS, 6 blocks/CU, 24 waves/CU.
__global__ __launch_bounds__(256) void qkvmadj_k(
    const unsigned short* __restrict__ A,
    const unsigned short* __restrict__ Bt,
    const float* __restrict__ bias,
    unsigned short* __restrict__ Qb,   // (B,H,L,64), pre-scaled by 0.125*log2e
    unsigned short* __restrict__ Kb,   // (B,H,L,64)
    unsigned short* __restrict__ Vt,   // (B,H,64,L)
    const float* __restrict__ adj,
    const int* __restrict__ mask,
    unsigned short* __restrict__ madj) {
    const int K = DIM;
    __shared__ unsigned short As[64][64];     //  8 KiB
    __shared__ unsigned short Bs[128][64];    // 16 KiB

    if (blockIdx.x < 256) {            // ---- madj stream ----
        int t = blockIdx.x * 256 + threadIdx.x;
        const unsigned short NEG = 0xFE96;  // bf16(-9.97e37)
#pragma unroll 1
        for (int it = 0; it < 16; ++it, t += 65536) {
            size_t i = (size_t)t * 8;
            float4 a0 = *(const float4*)(adj + i);
            float4 a1 = *(const float4*)(adj + i + 4);
            int4 m0 = *(const int4*)(mask + i);
            int4 m1 = *(const int4*)(mask + i + 4);
            ushort4 o0, o1;
            o0.x = m0.x ? f2bf(a0.x) : NEG; o0.y = m0.y ? f2bf(a0.y) : NEG;
            o0.z = m0.z ? f2bf(a0.z) : NEG; o0.w = m0.w ? f2bf(a0.w) : NEG;
            o1.x = m1.x ? f2bf(a1.x) : NEG; o1.y = m1.y ? f2bf(a1.y) : NEG;
            o1.z = m1.z ? f2bf(a1.z) : NEG; o1.w = m1.w ? f2bf(a1.w) : NEG;
            *(ushort4*)(madj + i) = o0;
            *(ushort4*)(madj + i + 4) = o1;
        }
        return;
    }

    int bid = blockIdx.x - 256;
    int tid = threadIdx.x;
    int lane = tid & 63, wave = tid >> 6;
    int l15 = lane & 15, g = lane >> 4;
    int wr = wave >> 1, wc = wave & 1;
    int bm = bid / (N3 / 128), bn = bid % (N3 / 128);   // 64 x 24 tiles

    const f32x4 fz = {0.f, 0.f, 0.f, 0.f};
    f32x4 acc[2][4];
#pragma unroll
    for (int m = 0; m < 2; ++m)
#pragma unroll
        for (int n = 0; n < 4; ++n) acc[m][n] = fz;

    int r8 = lane >> 3, u = lane & 7;
    int su = (u ^ r8) << 3;                 // pre-swizzled source column (elements)
    const unsigned short* Ap = A + (size_t)(bm * 64) * K;
    const unsigned short* Bp = Bt + (size_t)(bn * 128) * K;

    for (int k0 = 0; k0 < K; k0 += 64) {
        __syncthreads();
#pragma unroll
        for (int i = 0; i < 2; ++i) {
            int row = i * 32 + wave * 8 + r8;
            GLL(Ap + (size_t)row * K + k0 + su, &As[i * 32 + wave * 8][0]);
        }
#pragma unroll
        for (int i = 0; i < 4; ++i) {
            int row = i * 32 + wave * 8 + r8;
            GLL(Bp + (size_t)row * K + k0 + su, &Bs[i * 32 + wave * 8][0]);
        }
        __syncthreads();
#pragma unroll
        for (int kk = 0; kk < 2; ++kk) {
            bf16x8 af[2], bfr[4];
            int uu = kk * 4 + g;
#pragma unroll
            for (int m = 0; m < 2; ++m)
                af[m] = *(const bf16x8*)&As[wr * 32 + m * 16 + l15][(uu ^ (l15 & 7)) << 3];
#pragma unroll
            for (int n = 0; n < 4; ++n)
                bfr[n] = *(const bf16x8*)&Bs[wc * 64 + n * 16 + l15][(uu ^ (l15 & 7)) << 3];
#pragma unroll
            for (int m = 0; m < 2; ++m)
#pragma unroll
                for (int n = 0; n < 4; ++n)
                    acc[m][n] = __builtin_amdgcn_mfma_f32_16x16x32_bf16(af[m], bfr[n], acc[m][n], 0, 0, 0);
        }
    }
#pragma unroll
    for (int m = 0; m < 2; ++m)
#pragma unroll
        for (int n = 0; n < 4; ++n) {
            int ng = bn * 128 + wc * 64 + n * 16 + l15;
            float bv = bias[ng];
            int h = ng / 192, c = ng % 192;
#pragma unroll
            for (int r = 0; r < 4; ++r) {
                int mg = bm * 64 + wr * 32 + m * 16 + g * 4 + r;
                int b = mg >> 11, l = mg & (SL - 1);
                float v = acc[m][n][r] + bv;
                if (c < 64)
                    Qb[((size_t)(b * NH + h) * SL + l) * 64 + c] = f2bf(v * 0.18033688f); // 0.125*log2e
                else if (c < 128)
                    Kb[((size_t)(b * NH + h) * SL + l) * 64 + (c - 64)] = f2bf(v);
                else
                    Vt[((size_t)(b * NH + h) * 64 + (c - 128)) * SL + l] = f2bf(v);
            }
        }
}

// ---------------- fused flash attention (R8-exact: VGPR 64, 1 barrier/tile) ----------------
__global__ __launch_bounds__(256) void attn_k(
    const unsigned short* __restrict__ Qb,
    const unsigned short* __restrict__ Kb,
    const unsigned short* __restrict__ Vt,
    const unsigned short* __restrict__ madj,  // (B,L,L) bf16, mask pre-applied
    const float* __restrict__ gamma,
    unsigned short* __restrict__ attout) {    // (B,L,D) bf16
    __shared__ unsigned short Ks[2][64][64];  // linear, XOR-swizzled content
    __shared__ unsigned short Vs[2][64][64];
    __shared__ unsigned Ps[4][16][32];        // per-wave packed-bf16 P, XOR-swizzled u32 cols

    int tid = threadIdx.x, wave = tid >> 6, lane = tid & 63;
    int l15 = lane & 15, g = lane >> 4;
    int logical = ((blockIdx.x & 7) << 7) | (blockIdx.x >> 3);
    int h = logical & 15;
    int gq = logical >> 4;
    int qb = gq & 31;
    int b = gq >> 5;

    size_t bh = (size_t)(b * NH + h);
    const unsigned short* Qp = Qb + bh * SL * 64;
    const unsigned short* Kp = Kb + bh * SL * 64;
    const unsigned short* Vp = Vt + bh * 64 * SL;

    float slope = (h < 8) ? -1.44269504f / (float)(2 << h) : 0.0f;
    float gam = gamma[h] * 1.44269504f;

    int qrow = qb * 64 + wave * 16 + l15;
    bf16x8 qf0 = *(const bf16x8*)&Qp[(size_t)qrow * 64 + g * 8];
    bf16x8 qf1 = *(const bf16x8*)&Qp[(size_t)qrow * 64 + 32 + g * 8];

    const unsigned short* mrow_p = madj + ((size_t)b * SL + qrow) * SL + 4 * g;

    float mrow = -3.0e38f, lrow = 0.f;
    const f32x4 fz = {0.f, 0.f, 0.f, 0.f};
    f32x4 o[4];
#pragma unroll
    for (int dt = 0; dt < 4; ++dt) o[dt] = fz;

    int bpa = 80 * g;              // bpermute src-lane 20g+r
    unsigned xsw = (unsigned)((l15 & 7) << 2);

    int r8 = lane >> 3, u = lane & 7;
    int su = (u ^ r8) << 3;        // pre-swizzled source column (elements)

    // prologue: stage tile 0 into buffer 0; madj tile 0 into registers
#pragma unroll
    for (int i = 0; i < 2; ++i) {
        int row = i * 32 + wave * 8 + r8;
        GLL(Kp + ((size_t)row << 6) + su, &Ks[0][i * 32 + wave * 8][0]);
        GLL(Vp + (size_t)row * SL + su, &Vs[0][i * 32 + wave * 8][0]);
    }
    ushort4 mv_cur[4], mv_nxt[4];
#pragma unroll
    for (int jt = 0; jt < 4; ++jt) mv_cur[jt] = *(const ushort4*)(mrow_p + 16 * jt);

    for (int jb = 0; jb < 32; ++jb) {
        int bb = jb & 1;
        __syncthreads();   // drains vmcnt: buf[bb] + mv for this tile are resident

        // issue next tile's staging: K/V -> LDS (other buffer), madj -> regs.
        // Nothing below consumes these until after the NEXT barrier -> latency hidden.
        if (jb < 31) {
#pragma unroll
            for (int i = 0; i < 2; ++i) {
                int row = i * 32 + wave * 8 + r8;
                GLL(Kp + ((size_t)((jb + 1) * 64 + row) << 6) + su, &Ks[bb ^ 1][i * 32 + wave * 8][0]);
                GLL(Vp + (size_t)row * SL + (jb + 1) * 64 + su, &Vs[bb ^ 1][i * 32 + wave * 8][0]);
            }
#pragma unroll
            for (int jt = 0; jt < 4; ++jt)
                mv_nxt[jt] = *(const ushort4*)(mrow_p + (jb + 1) * 64 + 16 * jt);
        }

        // S^T = K Q^T : D[col = q-row = l15][row = k-local = 4g+r]
        f32x4 s[4];
        __builtin_amdgcn_s_setprio(1);
#pragma unroll
        for (int jt = 0; jt < 4; ++jt) {
            int row = jt * 16 + l15;
            bf16x8 kf0 = *(const bf16x8*)&Ks[bb][row][(g ^ (l15 & 7)) << 3];
            bf16x8 kf1 = *(const bf16x8*)&Ks[bb][row][((4 + g) ^ (l15 & 7)) << 3];
            s[jt] = __builtin_amdgcn_mfma_f32_16x16x32_bf16(kf0, qf0, fz, 0, 0, 0);
            s[jt] = __builtin_amdgcn_mfma_f32_16x16x32_bf16(kf1, qf1, s[jt], 0, 0, 0);
        }
        __builtin_amdgcn_s_setprio(0);

        // scores: val[4jt+r] for k = 16jt + 4g + r  (mv_cur already resident -> no vmem wait)
        float val[16];
        float d0 = (float)(qrow - jb * 64 - 4 * g);
#pragma unroll
        for (int jt = 0; jt < 4; ++jt) {
            float djt = d0 - (float)(16 * jt);
            val[4 * jt + 0] = fmaf(gam, bf2f(mv_cur[jt].x), fmaf(slope, fabsf(djt),       s[jt][0]));
            val[4 * jt + 1] = fmaf(gam, bf2f(mv_cur[jt].y), fmaf(slope, fabsf(djt - 1.f), s[jt][1]));
            val[4 * jt + 2] = fmaf(gam, bf2f(mv_cur[jt].z), fmaf(slope, fabsf(djt - 2.f), s[jt][2]));
            val[4 * jt + 3] = fmaf(gam, bf2f(mv_cur[jt].w), fmaf(slope, fabsf(djt - 3.f), s[jt][3]));
        }

        // row max: in-lane tree + cross-group
        float m0 = fmaxf(fmaxf(val[0], val[1]), fmaxf(val[2], val[3]));
        float m1 = fmaxf(fmaxf(val[4], val[5]), fmaxf(val[6], val[7]));
        float m2 = fmaxf(fmaxf(val[8], val[9]), fmaxf(val[10], val[11]));
        float m3 = fmaxf(fmaxf(val[12], val[13]), fmaxf(val[14], val[15]));
        float mx = fmaxf(fmaxf(m0, m1), fmaxf(m2, m3));
        mx = fmaxf(mx, __shfl_xor(mx, 16));
        mx = fmaxf(mx, __shfl_xor(mx, 32));

        // defer-max (T13)
        if (!__all(mx <= mrow + 8.0f)) {
            float mnew = fmaxf(mrow, mx);
            float sc = __builtin_exp2f(mrow - mnew);
            mrow = mnew;
            lrow *= sc;
            float scl[4];
#pragma unroll
            for (int r = 0; r < 4; ++r)
                scl[r] = __int_as_float(__builtin_amdgcn_ds_bpermute(bpa + 4 * r, __float_as_int(sc)));
#pragma unroll
            for (int dt = 0; dt < 4; ++dt)
#pragma unroll
                for (int r = 0; r < 4; ++r) o[dt][r] *= scl[r];
        }

        // p = exp2(val - mrow), row-sum
#pragma unroll
        for (int t = 0; t < 16; ++t) val[t] = __builtin_exp2f(val[t] - mrow);
        float s0 = (val[0] + val[1]) + (val[2] + val[3]);
        float s1 = (val[4] + val[5]) + (val[6] + val[7]);
        float s2 = (val[8] + val[9]) + (val[10] + val[11]);
        float s3 = (val[12] + val[13]) + (val[14] + val[15]);
        float rs = (s0 + s1) + (s2 + s3);
        rs += __shfl_xor(rs, 16);
        rs += __shfl_xor(rs, 32);
        lrow += rs;

        // pack P pairs (u32 idx = k/2), per-wave LDS (in-wave lgkm ordering only)
#pragma unroll
        for (int jt = 0; jt < 4; ++jt)
#pragma unroll
            for (int c = 0; c < 2; ++c) {
                union { unsigned u; __bf16 hh[2]; } pk;
                pk.hh[0] = (__bf16)val[4 * jt + 2 * c];
                pk.hh[1] = (__bf16)val[4 * jt + 2 * c + 1];
                Ps[wave][l15][(unsigned)(jt * 8 + g * 2 + c) ^ xsw] = pk.u;
            }

        // PV: A-frag = P[row=l15][k-halves], B-frag = Vs (swizzled read)
        __builtin_amdgcn_s_setprio(1);
#pragma unroll
        for (int h2 = 0; h2 < 2; ++h2) {
            union { uint4 u; bf16x8 v; } pr;
            pr.u = *(const uint4*)&Ps[wave][l15][(unsigned)(16 * h2 + 4 * g) ^ xsw];
#pragma unroll
            for (int dt = 0; dt < 4; ++dt) {
                bf16x8 vf = *(const bf16x8*)&Vs[bb][dt * 16 + l15][((h2 * 4 + g) ^ (l15 & 7)) << 3];
                o[dt] = __builtin_amdgcn_mfma_f32_16x16x32_bf16(pr.v, vf, o[dt], 0, 0, 0);
            }
        }
        __builtin_amdgcn_s_setprio(0);

        // rotate madj register buffer; the wait this forces coincides with the
        // barrier's own vmcnt drain (next loop top) -> no extra exposed latency
#pragma unroll
        for (int jt = 0; jt < 4; ++jt) mv_cur[jt] = mv_nxt[jt];
    }

    // epilogue: redistribute 1/l to output rows 4g+r, store
    float inv = 1.0f / lrow;
    float invr[4];
#pragma unroll
    for (int r = 0; r < 4; ++r)
        invr[r] = __int_as_float(__builtin_amdgcn_ds_bpermute(bpa + 4 * r, __float_as_int(inv)));
#pragma unroll
    for (int dt = 0; dt < 4; ++dt)
#pragma unroll
        for (int r = 0; r < 4; ++r) {
            int orow = qb * 64 + wave * 16 + 4 * g + r;
            attout[((size_t)b * SL + orow) * DIM + h * 64 + dt * 16 + l15] = f2bf(o[dt][r] * invr[r]);
        }
}

// ---------------- GEMM3: out = attout @ out_w + out_bias (fp32 out) ----------------
// 64x128 tiles -> 512 blocks = 2/CU
__global__ __launch_bounds__(256) void gemm_out_k(
    const unsigned short* __restrict__ A,    // (4096 x 1024) bf16
    const unsigned short* __restrict__ Bt,   // (1024 x 1024) bf16 (out_w^T)
    const float* __restrict__ bias,
    float* __restrict__ Out) {
    const int K = DIM;
    __shared__ unsigned short As[64][64];
    __shared__ unsigned short Bs[128][64];
    int tid = threadIdx.x;
    int lane = tid & 63, wave = tid >> 6;
    int l15 = lane & 15, g = lane >> 4;
    int wr = wave >> 1, wc = wave & 1;
    int bm = blockIdx.x >> 3, bn = blockIdx.x & 7;   // 64 x 8 tiles

    const f32x4 fz = {0.f, 0.f, 0.f, 0.f};
    f32x4 acc[2][4];
#pragma unroll
    for (int m = 0; m < 2; ++m)
#pragma unroll
        for (int n = 0; n < 4; ++n) acc[m][n] = fz;

    int r8 = lane >> 3, u = lane & 7;
    int su = (u ^ r8) << 3;
    const unsigned short* Ap = A + (size_t)(bm * 64) * K;
    const unsigned short* Bp = Bt + (size_t)(bn * 128) * K;

    for (int k0 = 0; k0 < K; k0 += 64) {
        __syncthreads();
#pragma unroll
        for (int i = 0; i < 2; ++i) {
            int row = i * 32 + wave * 8 + r8;
            GLL(Ap + (size_t)row * K + k0 + su, &As[i * 32 + wave * 8][0]);
        }
#pragma unroll
        for (int i = 0; i < 4; ++i) {
            int row = i * 32 + wave * 8 + r8;
            GLL(Bp + (size_t)row * K + k0 + su, &Bs[i * 32 + wave * 8][0]);
        }
        __syncthreads();
#pragma unroll
        for (int kk = 0; kk < 2; ++kk) {
            bf16x8 af[2], bfr[4];
            int uu = kk * 4 + g;
#pragma unroll
            for (int m = 0; m < 2; ++m)
                af[m] = *(const bf16x8*)&As[wr * 32 + m * 16 + l15][(uu ^ (l15 & 7)) << 3];
#pragma unroll
            for (int n = 0; n < 4; ++n)
                bfr[n] = *(const bf16x8*)&Bs[wc * 64 + n * 16 + l15][(uu ^ (l15 & 7)) << 3];
#pragma unroll
            for (int m = 0; m < 2; ++m)
#pragma unroll
                for (int n = 0; n < 4; ++n)
                    acc[m][n] = __builtin_amdgcn_mfma_f32_16x16x32_bf16(af[m], bfr[n], acc[m][n], 0, 0, 0);
        }
    }
#pragma unroll
    for (int m = 0; m < 2; ++m)
#pragma unroll
        for (int n = 0; n < 4; ++n) {
            int ng = bn * 128 + wc * 64 + n * 16 + l15;
            float bv = bias[ng];
#pragma unroll
            for (int r = 0; r < 4; ++r) {
                int mg = bm * 64 + wr * 32 + m * 16 + g * 4 + r;
                Out[(size_t)mg * DIM + ng] = acc[m][n][r] + bv;
            }
        }
}

extern "C" void kernel_launch(void* const* d_in, const int* in_sizes, int n_in,
                              void* d_out, int out_size, void* d_ws, size_t ws_size,
                              hipStream_t stream) {
    const float* x        = (const float*)d_in[0];
    const float* adj      = (const float*)d_in[1];
    const float* weights  = (const float*)d_in[2];
    const float* in_bias  = (const float*)d_in[3];
    const float* out_w    = (const float*)d_in[4];
    const float* out_bias = (const float*)d_in[5];
    const float* gamma    = (const float*)d_in[6];
    const int* mask       = (const int*)d_in[7];   // bool -> int32 per harness contract

    char* ws = (char*)d_ws;
    unsigned short* xbf    = (unsigned short*)(ws);              // 8 MiB
    unsigned short* wT     = (unsigned short*)(ws + 8388608);    // 6 MiB
    unsigned short* owT    = (unsigned short*)(ws + 14680064);   // 2 MiB
    unsigned short* Qb     = (unsigned short*)(ws + 16777216);   // 8 MiB
    unsigned short* Kb     = (unsigned short*)(ws + 25165824);   // 8 MiB
    unsigned short* Vt     = (unsigned short*)(ws + 33554432);   // 8 MiB
    unsigned short* attout = (unsigned short*)(ws + 41943040);   // 8 MiB (total 48 MiB)
    // madj (16.78 MB) lives in d_out: written by qkvmadj_k, read by attn_k,
    // dead before gemm_out_k overwrites d_out with the final result.
    unsigned short* madj   = (unsigned short*)d_out;
    float* out = (float*)d_out;

    prep_k<<<6144, 256, 0, stream>>>(x, weights, out_w, xbf, wT, owT);
    qkvmadj_k<<<1792, 256, 0, stream>>>(xbf, wT, in_bias, Qb, Kb, Vt, adj, mask, madj);
    attn_k<<<NB * NH * (SL / 64), 256, 0, stream>>>(Qb, Kb, Vt, madj, gamma, attout);
    gemm_out_k<<<512, 256, 0, stream>>>(attout, owT, out_bias, out);
}

// Round 13
// 167.403 us; speedup vs baseline: 1.1351x; 1.0070x over previous
//
#include <hip/hip_runtime.h>

#define NH 16
#define SL 2048
#define NB 2
#define DIM 1024
#define N3 3072

typedef __bf16 bf16x8 __attribute__((ext_vector_type(8)));
typedef float f32x4 __attribute__((ext_vector_type(4)));

// async global -> LDS, 16B per lane, wave-uniform LDS base (HW adds lane*16)
#define GLL(gsrc, ldst) \
    __builtin_amdgcn_global_load_lds((const __attribute__((address_space(1))) void*)(gsrc), \
                                     (__attribute__((address_space(3))) void*)(ldst), 16, 0, 0)

static __device__ __forceinline__ unsigned short f2bf(float f) {
    union { float f; unsigned u; } v; v.f = f;
    unsigned r = v.u + 0x7fffu + ((v.u >> 16) & 1u);   // RNE
    return (unsigned short)(r >> 16);
}
static __device__ __forceinline__ float bf2f(unsigned short u) {
    union { unsigned u; float f; } v; v.u = (unsigned)u << 16;
    return v.f;
}

// ---------------- prep (merged): x->bf16 | W^T->bf16  (owT moved to qkvmadj) ----------------
__global__ __launch_bounds__(256) void prep_k(const float* __restrict__ x,
                                              const float* __restrict__ w,
                                              unsigned short* __restrict__ xbf,
                                              unsigned short* __restrict__ wT) {
    __shared__ float tile[32][33];
    int blk = blockIdx.x;
    if (blk < 2048) {                     // cvt x -> xbf, 8 elems/lane
        int i = (blk * 256 + threadIdx.x) * 8;
        float4 v0 = *(const float4*)(x + i);
        float4 v1 = *(const float4*)(x + i + 4);
        ushort4 o0, o1;
        o0.x = f2bf(v0.x); o0.y = f2bf(v0.y); o0.z = f2bf(v0.z); o0.w = f2bf(v0.w);
        o1.x = f2bf(v1.x); o1.y = f2bf(v1.y); o1.z = f2bf(v1.z); o1.w = f2bf(v1.w);
        *(ushort4*)(xbf + i) = o0;
        *(ushort4*)(xbf + i + 4) = o1;
        return;
    }
    // weights (1024 x 3072) -> wT (3072 x 1024)
    int idx = blk - 2048;
    int bx = idx % (N3 / 32), by = idx / (N3 / 32);
    int tx = threadIdx.x & 31, ty = threadIdx.x >> 5;
    int c0 = bx * 32, r0 = by * 32;
#pragma unroll
    for (int i = 0; i < 4; ++i)
        tile[ty + i * 8][tx] = w[(size_t)(r0 + ty + i * 8) * N3 + (c0 + tx)];
    __syncthreads();
#pragma unroll
    for (int i = 0; i < 4; ++i)
        wT[(size_t)(c0 + ty + i * 8) * DIM + (r0 + tx)] = f2bf(tile[tx][ty + i * 8]);
}

// ---------------- merged: GEMM1 (qkv, 64x128 tiles) || fuse_madj || owT transpose ----------------
// blocks [0,256): madj stream.  blocks [256,1792): 64x128 gemm tiles.
// blocks [1792,2816): out_w^T transpose (hides under the madj HBM stream).
__global__ __launch_bounds__(256) void qkvmadj_k(
    const unsigned short* __restrict__ A,
    const unsigned short* __restrict__ Bt,
    const float* __restrict__ bias,
    unsigned short* __restrict__ Qb,   // (B,H,L,64), pre-scaled by 0.125*log2e
    unsigned short* __restrict__ Kb,   // (B,H,L,64)
    unsigned short* __restrict__ Vt,   // (B,H,64,L)
    const float* __restrict__ adj,
    const int* __restrict__ mask,
    unsigned short* __restrict__ madj,
    const float* __restrict__ ow,
    unsigned short* __restrict__ owT) {
    const int K = DIM;
    __shared__ unsigned short As[64][64];     //  8 KiB (reused as fp32 scratch by owT path)
    __shared__ unsigned short Bs[128][64];    // 16 KiB

    if (blockIdx.x < 256) {            // ---- madj stream ----
        int t = blockIdx.x * 256 + threadIdx.x;
        const unsigned short NEG = 0xFE96;  // bf16(-9.97e37)
#pragma unroll 1
        for (int it = 0; it < 16; ++it, t += 65536) {
            size_t i = (size_t)t * 8;
            float4 a0 = *(const float4*)(adj + i);
            float4 a1 = *(const float4*)(adj + i + 4);
            int4 m0 = *(const int4*)(mask + i);
            int4 m1 = *(const int4*)(mask + i + 4);
            ushort4 o0, o1;
            o0.x = m0.x ? f2bf(a0.x) : NEG; o0.y = m0.y ? f2bf(a0.y) : NEG;
            o0.z = m0.z ? f2bf(a0.z) : NEG; o0.w = m0.w ? f2bf(a0.w) : NEG;
            o1.x = m1.x ? f2bf(a1.x) : NEG; o1.y = m1.y ? f2bf(a1.y) : NEG;
            o1.z = m1.z ? f2bf(a1.z) : NEG; o1.w = m1.w ? f2bf(a1.w) : NEG;
            *(ushort4*)(madj + i) = o0;
            *(ushort4*)(madj + i + 4) = o1;
        }
        return;
    }

    if (blockIdx.x >= 1792) {          // ---- owT transpose (moved from prep) ----
        int idx = blockIdx.x - 1792;
        int bx = idx & 31, by = idx >> 5;        // (1024/32) x (1024/32)
        float (*tile)[33] = (float(*)[33])&As[0][0];   // 4224 B scratch inside As
        int tx = threadIdx.x & 31, ty = threadIdx.x >> 5;
        int c0 = bx * 32, r0 = by * 32;
#pragma unroll
        for (int i = 0; i < 4; ++i)
            tile[ty + i * 8][tx] = ow[(size_t)(r0 + ty + i * 8) * DIM + (c0 + tx)];
        __syncthreads();
#pragma unroll
        for (int i = 0; i < 4; ++i)
            owT[(size_t)(c0 + ty + i * 8) * DIM + (r0 + tx)] = f2bf(tile[tx][ty + i * 8]);
        return;
    }

    int bid = blockIdx.x - 256;
    int tid = threadIdx.x;
    int lane = tid & 63, wave = tid >> 6;
    int l15 = lane & 15, g = lane >> 4;
    int wr = wave >> 1, wc = wave & 1;
    int bm = bid / (N3 / 128), bn = bid % (N3 / 128);   // 64 x 24 tiles

    const f32x4 fz = {0.f, 0.f, 0.f, 0.f};
    f32x4 acc[2][4];
#pragma unroll
    for (int m = 0; m < 2; ++m)
#pragma unroll
        for (int n = 0; n < 4; ++n) acc[m][n] = fz;

    int r8 = lane >> 3, u = lane & 7;
    int su = (u ^ r8) << 3;                 // pre-swizzled source column (elements)
    const unsigned short* Ap = A + (size_t)(bm * 64) * K;
    const unsigned short* Bp = Bt + (size_t)(bn * 128) * K;

    for (int k0 = 0; k0 < K; k0 += 64) {
        __syncthreads();
#pragma unroll
        for (int i = 0; i < 2; ++i) {
            int row = i * 32 + wave * 8 + r8;
            GLL(Ap + (size_t)row * K + k0 + su, &As[i * 32 + wave * 8][0]);
        }
#pragma unroll
        for (int i = 0; i < 4; ++i) {
            int row = i * 32 + wave * 8 + r8;
            GLL(Bp + (size_t)row * K + k0 + su, &Bs[i * 32 + wave * 8][0]);
        }
        __syncthreads();
#pragma unroll
        for (int kk = 0; kk < 2; ++kk) {
            bf16x8 af[2], bfr[4];
            int uu = kk * 4 + g;
#pragma unroll
            for (int m = 0; m < 2; ++m)
                af[m] = *(const bf16x8*)&As[wr * 32 + m * 16 + l15][(uu ^ (l15 & 7)) << 3];
#pragma unroll
            for (int n = 0; n < 4; ++n)
                bfr[n] = *(const bf16x8*)&Bs[wc * 64 + n * 16 + l15][(uu ^ (l15 & 7)) << 3];
#pragma unroll
            for (int m = 0; m < 2; ++m)
#pragma unroll
                for (int n = 0; n < 4; ++n)
                    acc[m][n] = __builtin_amdgcn_mfma_f32_16x16x32_bf16(af[m], bfr[n], acc[m][n], 0, 0, 0);
        }
    }
#pragma unroll
    for (int m = 0; m < 2; ++m)
#pragma unroll
        for (int n = 0; n < 4; ++n) {
            int ng = bn * 128 + wc * 64 + n * 16 + l15;
            float bv = bias[ng];
            int h = ng / 192, c = ng % 192;
#pragma unroll
            for (int r = 0; r < 4; ++r) {
                int mg = bm * 64 + wr * 32 + m * 16 + g * 4 + r;
                int b = mg >> 11, l = mg & (SL - 1);
                float v = acc[m][n][r] + bv;
                if (c < 64)
                    Qb[((size_t)(b * NH + h) * SL + l) * 64 + c] = f2bf(v * 0.18033688f); // 0.125*log2e
                else if (c < 128)
                    Kb[((size_t)(b * NH + h) * SL + l) * 64 + (c - 64)] = f2bf(v);
                else
                    Vt[((size_t)(b * NH + h) * 64 + (c - 128)) * SL + l] = f2bf(v);
            }
        }
}

// ---------------- fused flash attention (R8-exact: VGPR 64, 1 barrier/tile) ----------------
__global__ __launch_bounds__(256) void attn_k(
    const unsigned short* __restrict__ Qb,
    const unsigned short* __restrict__ Kb,
    const unsigned short* __restrict__ Vt,
    const unsigned short* __restrict__ madj,  // (B,L,L) bf16, mask pre-applied
    const float* __restrict__ gamma,
    unsigned short* __restrict__ attout) {    // (B,L,D) bf16
    __shared__ unsigned short Ks[2][64][64];  // linear, XOR-swizzled content
    __shared__ unsigned short Vs[2][64][64];
    __shared__ unsigned Ps[4][16][32];        // per-wave packed-bf16 P, XOR-swizzled u32 cols

    int tid = threadIdx.x, wave = tid >> 6, lane = tid & 63;
    int l15 = lane & 15, g = lane >> 4;
    int logical = ((blockIdx.x & 7) << 7) | (blockIdx.x >> 3);
    int h = logical & 15;
    int gq = logical >> 4;
    int qb = gq & 31;
    int b = gq >> 5;

    size_t bh = (size_t)(b * NH + h);
    const unsigned short* Qp = Qb + bh * SL * 64;
    const unsigned short* Kp = Kb + bh * SL * 64;
    const unsigned short* Vp = Vt + bh * 64 * SL;

    float slope = (h < 8) ? -1.44269504f / (float)(2 << h) : 0.0f;
    float gam = gamma[h] * 1.44269504f;

    int qrow = qb * 64 + wave * 16 + l15;
    bf16x8 qf0 = *(const bf16x8*)&Qp[(size_t)qrow * 64 + g * 8];
    bf16x8 qf1 = *(const bf16x8*)&Qp[(size_t)qrow * 64 + 32 + g * 8];

    const unsigned short* mrow_p = madj + ((size_t)b * SL + qrow) * SL + 4 * g;

    float mrow = -3.0e38f, lrow = 0.f;
    const f32x4 fz = {0.f, 0.f, 0.f, 0.f};
    f32x4 o[4];
#pragma unroll
    for (int dt = 0; dt < 4; ++dt) o[dt] = fz;

    int bpa = 80 * g;              // bpermute src-lane 20g+r
    unsigned xsw = (unsigned)((l15 & 7) << 2);

    int r8 = lane >> 3, u = lane & 7;
    int su = (u ^ r8) << 3;        // pre-swizzled source column (elements)

    // prologue: stage tile 0 into buffer 0; madj tile 0 into registers
#pragma unroll
    for (int i = 0; i < 2; ++i) {
        int row = i * 32 + wave * 8 + r8;
        GLL(Kp + ((size_t)row << 6) + su, &Ks[0][i * 32 + wave * 8][0]);
        GLL(Vp + (size_t)row * SL + su, &Vs[0][i * 32 + wave * 8][0]);
    }
    ushort4 mv_cur[4], mv_nxt[4];
#pragma unroll
    for (int jt = 0; jt < 4; ++jt) mv_cur[jt] = *(const ushort4*)(mrow_p + 16 * jt);

    for (int jb = 0; jb < 32; ++jb) {
        int bb = jb & 1;
        __syncthreads();   // drains vmcnt: buf[bb] + mv for this tile are resident

        // issue next tile's staging: K/V -> LDS (other buffer), madj -> regs.
        // Nothing below consumes these until after the NEXT barrier -> latency hidden.
        if (jb < 31) {
#pragma unroll
            for (int i = 0; i < 2; ++i) {
                int row = i * 32 + wave * 8 + r8;
                GLL(Kp + ((size_t)((jb + 1) * 64 + row) << 6) + su, &Ks[bb ^ 1][i * 32 + wave * 8][0]);
                GLL(Vp + (size_t)row * SL + (jb + 1) * 64 + su, &Vs[bb ^ 1][i * 32 + wave * 8][0]);
            }
#pragma unroll
            for (int jt = 0; jt < 4; ++jt)
                mv_nxt[jt] = *(const ushort4*)(mrow_p + (jb + 1) * 64 + 16 * jt);
        }

        // S^T = K Q^T : D[col = q-row = l15][row = k-local = 4g+r]
        f32x4 s[4];
        __builtin_amdgcn_s_setprio(1);
#pragma unroll
        for (int jt = 0; jt < 4; ++jt) {
            int row = jt * 16 + l15;
            bf16x8 kf0 = *(const bf16x8*)&Ks[bb][row][(g ^ (l15 & 7)) << 3];
            bf16x8 kf1 = *(const bf16x8*)&Ks[bb][row][((4 + g) ^ (l15 & 7)) << 3];
            s[jt] = __builtin_amdgcn_mfma_f32_16x16x32_bf16(kf0, qf0, fz, 0, 0, 0);
            s[jt] = __builtin_amdgcn_mfma_f32_16x16x32_bf16(kf1, qf1, s[jt], 0, 0, 0);
        }
        __builtin_amdgcn_s_setprio(0);

        // scores: val[4jt+r] for k = 16jt + 4g + r  (mv_cur already resident -> no vmem wait)
        float val[16];
        float d0 = (float)(qrow - jb * 64 - 4 * g);
#pragma unroll
        for (int jt = 0; jt < 4; ++jt) {
            float djt = d0 - (float)(16 * jt);
            val[4 * jt + 0] = fmaf(gam, bf2f(mv_cur[jt].x), fmaf(slope, fabsf(djt),       s[jt][0]));
            val[4 * jt + 1] = fmaf(gam, bf2f(mv_cur[jt].y), fmaf(slope, fabsf(djt - 1.f), s[jt][1]));
            val[4 * jt + 2] = fmaf(gam, bf2f(mv_cur[jt].z), fmaf(slope, fabsf(djt - 2.f), s[jt][2]));
            val[4 * jt + 3] = fmaf(gam, bf2f(mv_cur[jt].w), fmaf(slope, fabsf(djt - 3.f), s[jt][3]));
        }

        // row max: in-lane tree + cross-group
        float m0 = fmaxf(fmaxf(val[0], val[1]), fmaxf(val[2], val[3]));
        float m1 = fmaxf(fmaxf(val[4], val[5]), fmaxf(val[6], val[7]));
        float m2 = fmaxf(fmaxf(val[8], val[9]), fmaxf(val[10], val[11]));
        float m3 = fmaxf(fmaxf(val[12], val[13]), fmaxf(val[14], val[15]));
        float mx = fmaxf(fmaxf(m0, m1), fmaxf(m2, m3));
        mx = fmaxf(mx, __shfl_xor(mx, 16));
        mx = fmaxf(mx, __shfl_xor(mx, 32));

        // defer-max (T13)
        if (!__all(mx <= mrow + 8.0f)) {
            float mnew = fmaxf(mrow, mx);
            float sc = __builtin_exp2f(mrow - mnew);
            mrow = mnew;
            lrow *= sc;
            float scl[4];
#pragma unroll
            for (int r = 0; r < 4; ++r)
                scl[r] = __int_as_float(__builtin_amdgcn_ds_bpermute(bpa + 4 * r, __float_as_int(sc)));
#pragma unroll
            for (int dt = 0; dt < 4; ++dt)
#pragma unroll
                for (int r = 0; r < 4; ++r) o[dt][r] *= scl[r];
        }

        // p = exp2(val - mrow), row-sum
#pragma unroll
        for (int t = 0; t < 16; ++t) val[t] = __builtin_exp2f(val[t] - mrow);
        float s0 = (val[0] + val[1]) + (val[2] + val[3]);
        float s1 = (val[4] + val[5]) + (val[6] + val[7]);
        float s2 = (val[8] + val[9]) + (val[10] + val[11]);
        float s3 = (val[12] + val[13]) + (val[14] + val[15]);
        float rs = (s0 + s1) + (s2 + s3);
        rs += __shfl_xor(rs, 16);
        rs += __shfl_xor(rs, 32);
        lrow += rs;

        // pack P pairs (u32 idx = k/2), per-wave LDS (in-wave lgkm ordering only)
#pragma unroll
        for (int jt = 0; jt < 4; ++jt)
#pragma unroll
            for (int c = 0; c < 2; ++c) {
                union { unsigned u; __bf16 hh[2]; } pk;
                pk.hh[0] = (__bf16)val[4 * jt + 2 * c];
                pk.hh[1] = (__bf16)val[4 * jt + 2 * c + 1];
                Ps[wave][l15][(unsigned)(jt * 8 + g * 2 + c) ^ xsw] = pk.u;
            }

        // PV: A-frag = P[row=l15][k-halves], B-frag = Vs (swizzled read)
        __builtin_amdgcn_s_setprio(1);
#pragma unroll
        for (int h2 = 0; h2 < 2; ++h2) {
            union { uint4 u; bf16x8 v; } pr;
            pr.u = *(const uint4*)&Ps[wave][l15][(unsigned)(16 * h2 + 4 * g) ^ xsw];
#pragma unroll
            for (int dt = 0; dt < 4; ++dt) {
                bf16x8 vf = *(const bf16x8*)&Vs[bb][dt * 16 + l15][((h2 * 4 + g) ^ (l15 & 7)) << 3];
                o[dt] = __builtin_amdgcn_mfma_f32_16x16x32_bf16(pr.v, vf, o[dt], 0, 0, 0);
            }
        }
        __builtin_amdgcn_s_setprio(0);

        // rotate madj register buffer; the wait this forces coincides with the
        // barrier's own vmcnt drain (next loop top) -> no extra exposed latency
#pragma unroll
        for (int jt = 0; jt < 4; ++jt) mv_cur[jt] = mv_nxt[jt];
    }

    // epilogue: redistribute 1/l to output rows 4g+r, store
    float inv = 1.0f / lrow;
    float invr[4];
#pragma unroll
    for (int r = 0; r < 4; ++r)
        invr[r] = __int_as_float(__builtin_amdgcn_ds_bpermute(bpa + 4 * r, __float_as_int(inv)));
#pragma unroll
    for (int dt = 0; dt < 4; ++dt)
#pragma unroll
        for (int r = 0; r < 4; ++r) {
            int orow = qb * 64 + wave * 16 + 4 * g + r;
            attout[((size_t)b * SL + orow) * DIM + h * 64 + dt * 16 + l15] = f2bf(o[dt][r] * invr[r]);
        }
}

// ---------------- GEMM3: out = attout @ out_w + out_bias (fp32 out) ----------------
// 64x64 tiles -> 1024 blocks = 4/CU, 16 waves/CU (was 2/CU at 64x128)
__global__ __launch_bounds__(256) void gemm_out_k(
    const unsigned short* __restrict__ A,    // (4096 x 1024) bf16
    const unsigned short* __restrict__ Bt,   // (1024 x 1024) bf16 (out_w^T)
    const float* __restrict__ bias,
    float* __restrict__ Out) {
    const int K = DIM;
    __shared__ unsigned short As[64][64];
    __shared__ unsigned short Bs[64][64];
    int tid = threadIdx.x;
    int lane = tid & 63, wave = tid >> 6;
    int l15 = lane & 15, g = lane >> 4;
    int wr = wave >> 1, wc = wave & 1;
    int bm = blockIdx.x >> 4, bn = blockIdx.x & 15;   // 64 x 16 tiles

    const f32x4 fz = {0.f, 0.f, 0.f, 0.f};
    f32x4 acc[2][2];
#pragma unroll
    for (int m = 0; m < 2; ++m)
#pragma unroll
        for (int n = 0; n < 2; ++n) acc[m][n] = fz;

    int r8 = lane >> 3, u = lane & 7;
    int su = (u ^ r8) << 3;
    const unsigned short* Ap = A + (size_t)(bm * 64) * K;
    const unsigned short* Bp = Bt + (size_t)(bn * 64) * K;

    for (int k0 = 0; k0 < K; k0 += 64) {
        __syncthreads();
#pragma unroll
        for (int i = 0; i < 2; ++i) {
            int rowbase = i * 32 + wave * 8;
            GLL(Ap + (size_t)(rowbase + r8) * K + k0 + su, &As[rowbase][0]);
            GLL(Bp + (size_t)(rowbase + r8) * K + k0 + su, &Bs[rowbase][0]);
        }
        __syncthreads();
#pragma unroll
        for (int kk = 0; kk < 2; ++kk) {
            bf16x8 af[2], bfr[2];
            int uu = kk * 4 + g;
#pragma unroll
            for (int m = 0; m < 2; ++m)
                af[m] = *(const bf16x8*)&As[wr * 32 + m * 16 + l15][(uu ^ (l15 & 7)) << 3];
#pragma unroll
            for (int n = 0; n < 2; ++n)
                bfr[n] = *(const bf16x8*)&Bs[wc * 32 + n * 16 + l15][(uu ^ (l15 & 7)) << 3];
#pragma unroll
            for (int m = 0; m < 2; ++m)
#pragma unroll
                for (int n = 0; n < 2; ++n)
                    acc[m][n] = __builtin_amdgcn_mfma_f32_16x16x32_bf16(af[m], bfr[n], acc[m][n], 0, 0, 0);
        }
    }
#pragma unroll
    for (int m = 0; m < 2; ++m)
#pragma unroll
        for (int n = 0; n < 2; ++n) {
            int ng = bn * 64 + wc * 32 + n * 16 + l15;
            float bv = bias[ng];
#pragma unroll
            for (int r = 0; r < 4; ++r) {
                int mg = bm * 64 + wr * 32 + m * 16 + g * 4 + r;
                Out[(size_t)mg * DIM + ng] = acc[m][n][r] + bv;
            }
        }
}

extern "C" void kernel_launch(void* const* d_in, const int* in_sizes, int n_in,
                              void* d_out, int out_size, void* d_ws, size_t ws_size,
                              hipStream_t stream) {
    const float* x        = (const float*)d_in[0];
    const float* adj      = (const float*)d_in[1];
    const float* weights  = (const float*)d_in[2];
    const float* in_bias  = (const float*)d_in[3];
    const float* out_w    = (const float*)d_in[4];
    const float* out_bias = (const float*)d_in[5];
    const float* gamma    = (const float*)d_in[6];
    const int* mask       = (const int*)d_in[7];   // bool -> int32 per harness contract

    char* ws = (char*)d_ws;
    unsigned short* xbf    = (unsigned short*)(ws);              // 8 MiB
    unsigned short* wT     = (unsigned short*)(ws + 8388608);    // 6 MiB
    unsigned short* owT    = (unsigned short*)(ws + 14680064);   // 2 MiB
    unsigned short* Qb     = (unsigned short*)(ws + 16777216);   // 8 MiB
    unsigned short* Kb     = (unsigned short*)(ws + 25165824);   // 8 MiB
    unsigned short* Vt     = (unsigned short*)(ws + 33554432);   // 8 MiB
    unsigned short* attout = (unsigned short*)(ws + 41943040);   // 8 MiB (total 48 MiB)
    // madj (16.78 MB) lives in d_out: written by qkvmadj_k, read by attn_k,
    // dead before gemm_out_k overwrites d_out with the final result.
    unsigned short* madj   = (unsigned short*)d_out;
    float* out = (float*)d_out;

    prep_k<<<5120, 256, 0, stream>>>(x, weights, xbf, wT);
    qkvmadj_k<<<2816, 256, 0, stream>>>(xbf, wT, in_bias, Qb, Kb, Vt, adj, mask, madj, out_w, owT);
    attn_k<<<NB * NH * (SL / 64), 256, 0, stream>>>(Qb, Kb, Vt, madj, gamma, attout);
    gemm_out_k<<<1024, 256, 0, stream>>>(attout, owT, out_bias, out);
}